// Round 10
// baseline (107.838 us; speedup 1.0000x reference)
//
#include <hip/hip_runtime.h>
#include <hip/hip_bf16.h>
#include <math.h>

// Problem dims
#define Bn 16
#define Sn 128
#define Rn 4
#define Ln 50
#define En 64
#define Hn 64
#define Vn 1000
#define G3 192          // 3*H
#define PH1n 256
#define PH2n 64
#define NSEQ (Bn*Sn*Rn) // 8192
#define NROW (Bn*Sn)    // 2048
#define GP 16           // peer sequences per block (MFMA M-tile)

typedef short bf16x8 __attribute__((ext_vector_type(8)));
typedef float f32x4  __attribute__((ext_vector_type(4)));
typedef _Float16 half2_t __attribute__((ext_vector_type(2)));
typedef unsigned uint4v __attribute__((ext_vector_type(4)));

__device__ __forceinline__ unsigned short f2bf(float x) {
    union { float f; unsigned u; } v; v.f = x;
    unsigned r = v.u + 0x7FFF + ((v.u >> 16) & 1);   // RNE
    return (unsigned short)(r >> 16);
}
__device__ __forceinline__ float bf2f(unsigned short b) {
    union { unsigned u; float f; } v; v.u = ((unsigned)b) << 16; return v.f;
}
__device__ __forceinline__ unsigned cvtpk_bf16(float lo, float hi) {
    unsigned r;
    asm volatile("v_cvt_pk_bf16_f32 %0, %1, %2" : "=v"(r) : "v"(lo), "v"(hi));
    return r;
}
// fast sigmoid/tanh: v_exp_f32 (2^x) + v_rcp_f32
__device__ __forceinline__ float fsig(float x) {
    float e = __builtin_amdgcn_exp2f(-x * 1.442695041f);
    return __builtin_amdgcn_rcpf(1.0f + e);
}
__device__ __forceinline__ float ftanh(float x) {
    float e = __builtin_amdgcn_exp2f(x * 2.885390082f);
    return 1.0f - 2.0f * __builtin_amdgcn_rcpf(e + 1.0f);
}

// Raw barrier: LDS-drain only; global loads/stores float across (no vmcnt(0)).
#define BAR() do { asm volatile("s_waitcnt lgkmcnt(0)" ::: "memory"); \
                   __builtin_amdgcn_s_barrier(); \
                   __builtin_amdgcn_sched_barrier(0); } while (0)

// Issue 3 gate-loads via un-sinkable volatile asm: p[0], p[64], p[128].
__device__ __forceinline__ void gload3(const float* p, float& a, float& b, float& c) {
    asm volatile("global_load_dword %0, %3, off\n\t"
                 "global_load_dword %1, %3, off offset:256\n\t"
                 "global_load_dword %2, %3, off offset:512"
                 : "=&v"(a), "=&v"(b), "=&v"(c) : "v"(p));
}

// ---------------------------------------------------------------------------
// Kernel A: blocks [0, Vn)       : pre_h[v][j] = bi_h[j] + emb[v]·Wi_h[:,j]
//           blocks [Vn, Vn+NROW) : xw[row][j]  = bi_x[j] + emb[id]·Wi_x[:,j]
//                                  + y_sh·Wi_x[64,j]
// ---------------------------------------------------------------------------
__global__ __launch_bounds__(192) void precompute_tab(
    const float* __restrict__ emb,
    const float* __restrict__ Wi_h, const float* __restrict__ bi_h,
    const float* __restrict__ Wi_x, const float* __restrict__ bi_x,
    const int*   __restrict__ intra_x, const float* __restrict__ y,
    float* __restrict__ pre_h, float* __restrict__ xw)
{
    const int bx = blockIdx.x;
    const int j = threadIdx.x;            // 0..191
    __shared__ float e_l[En];
    if (bx < Vn) {
        if (j < En) e_l[j] = emb[bx * En + j];
        __syncthreads();
        float a = bi_h[j];
#pragma unroll 8
        for (int k = 0; k < En; ++k) a = fmaf(e_l[k], Wi_h[k * G3 + j], a);
        pre_h[bx * G3 + j] = a;
    } else {
        const int row = bx - Vn;          // row = b*Sn + t
        const int id = intra_x[row];
        const float lb = (row & (Sn - 1)) ? y[row - 1] : 0.0f;
        if (j < En) e_l[j] = emb[id * En + j];
        __syncthreads();
        float a = bi_x[j];
#pragma unroll 8
        for (int k = 0; k < En; ++k) a = fmaf(e_l[k], Wi_x[k * G3 + j], a);
        a = fmaf(lb, Wi_x[64 * G3 + j], a);
        xw[row * G3 + j] = a;
    }
}

// ---------------------------------------------------------------------------
// Kernel B:
//   blocks 0..3    : intra GRU — 1 wave = 1 sequence, fdot2, barrier-free
//   blocks 4..515  : peer GRU  — 16 seqs/block, bf16 MFMA, raw barriers
// ---------------------------------------------------------------------------
__global__ __launch_bounds__(256, 2) void gru_fused(
    const float* __restrict__ pre_h, const float* __restrict__ xw,
    const int*   __restrict__ inter_his, const int* __restrict__ inter_len,
    const float* __restrict__ Wh_h, const float* __restrict__ bh_h,
    const float* __restrict__ Wi_h,
    const float* __restrict__ Wh_x, const float* __restrict__ bh_x,
    unsigned short* __restrict__ mrv16, float* __restrict__ h_x)
{
    __shared__ __align__(16) unsigned short h16[2][GP * 64];  // peer dbuf
    __shared__ __align__(16) _Float16 hx_s[4][64];            // intra exch
    __shared__ int   ids_l[GP][Ln];
    __shared__ float labs_l[GP][Ln];

    const int tid = threadIdx.x;
    const int lane = tid & 63, w = tid >> 6;

    if (blockIdx.x >= 4) {
        // =============== PEER GRU (MFMA, raw barriers) ===============
        const int seq0 = ((int)blockIdx.x - 4) * GP;
        const int n_ = lane & 15, kb = lane >> 4;
        const int jh = w * 16 + n_;
        const int rbase = kb * 4;

        const unsigned arow = (unsigned)(n_ * 128);
        const unsigned ac0  = (unsigned)((kb * 16) ^ ((n_ & 7) << 4));
        const unsigned ac1  = (unsigned)((64 + kb * 16) ^ ((n_ & 7) << 4));
        unsigned woff[4];
#pragma unroll
        for (int q = 0; q < 4; ++q) {
            int r = rbase + q;
            woff[q] = (unsigned)(r * 128 + ((jh * 2) ^ ((r & 7) << 4)));
        }
        for (int i = tid; i < GP * 64; i += 256) h16[0][i] = 0;
        for (int i = tid; i < GP * Ln; i += 256) {
            int r = i / Ln, t = i % Ln;
            int base = ((seq0 + r) * Ln + t) * 2;
            ids_l[r][t]  = inter_his[base];
            labs_l[r][t] = (float)inter_his[base + 1];
        }
        bf16x8 bfr[3][2];
#pragma unroll
        for (int g = 0; g < 3; ++g)
#pragma unroll
            for (int kh = 0; kh < 2; ++kh) {
                bf16x8 v;
#pragma unroll
                for (int i = 0; i < 8; ++i)
                    v[i] = (short)f2bf(Wh_h[(kh * 32 + kb * 8 + i) * G3 + g * 64 + jh]);
                bfr[g][kh] = v;
            }
        const float bhr = bh_h[jh], bhz = bh_h[64 + jh], bhn = bh_h[128 + jh];
        const float wlr = Wi_h[64 * G3 + jh];
        const float wlz = Wi_h[64 * G3 + 64 + jh];
        const float wln = Wi_h[64 * G3 + 128 + jh];
        int lenr[4];
#pragma unroll
        for (int q = 0; q < 4; ++q) lenr[q] = inter_len[seq0 + rbase + q];
        float hprev[4] = {0.f, 0.f, 0.f, 0.f};

        float Ar[4], Az[4], An_[4], Al[4];
        float Br[4], Bz[4], Bn_[4], Bl[4];
#pragma unroll
        for (int q = 0; q < 4; ++q) {
            int id = ids_l[rbase + q][0];
            Al[q] = labs_l[rbase + q][0];
            gload3(pre_h + id * G3 + jh, Ar[q], Az[q], An_[q]);
        }
        __syncthreads();   // setup (full drain once)

        auto step = [&](int t, int cur,
                        float (&gr)[4], float (&gz)[4], float (&gn)[4], float (&gl)[4],
                        float (&pr)[4], float (&pz)[4], float (&pn)[4], float (&pl)[4]) {
            const char* rb = (const char*)&h16[cur][0];
            bf16x8 a0 = *(const bf16x8*)(rb + arow + ac0);
            bf16x8 a1 = *(const bf16x8*)(rb + arow + ac1);
            const int tn = (t + 1 < Ln) ? t + 1 : t;
#pragma unroll
            for (int q = 0; q < 4; ++q) {
                int id = ids_l[rbase + q][tn];
                pl[q] = labs_l[rbase + q][tn];
                gload3(pre_h + id * G3 + jh, pr[q], pz[q], pn[q]);
            }
            f32x4 z4 = {0.f, 0.f, 0.f, 0.f};
            f32x4 acc0 = __builtin_amdgcn_mfma_f32_16x16x32_bf16(a0, bfr[0][0], z4, 0, 0, 0);
            f32x4 acc1 = __builtin_amdgcn_mfma_f32_16x16x32_bf16(a0, bfr[1][0], z4, 0, 0, 0);
            f32x4 acc2 = __builtin_amdgcn_mfma_f32_16x16x32_bf16(a0, bfr[2][0], z4, 0, 0, 0);
            acc0 = __builtin_amdgcn_mfma_f32_16x16x32_bf16(a1, bfr[0][1], acc0, 0, 0, 0);
            acc1 = __builtin_amdgcn_mfma_f32_16x16x32_bf16(a1, bfr[1][1], acc1, 0, 0, 0);
            acc2 = __builtin_amdgcn_mfma_f32_16x16x32_bf16(a1, bfr[2][1], acc2, 0, 0, 0);

            asm volatile("s_waitcnt vmcnt(12)" ::: "memory");
            __builtin_amdgcn_sched_barrier(0);

            char* wb = (char*)&h16[cur ^ 1][0];
            float hn[4];
#pragma unroll
            for (int q = 0; q < 4; ++q) {
                float xr = fmaf(gl[q], wlr, gr[q]);
                float xz = fmaf(gl[q], wlz, gz[q]);
                float xn = fmaf(gl[q], wln, gn[q]);
                float rg = fsig(xr + acc0[q] + bhr);
                float zg = fsig(xz + acc1[q] + bhz);
                float ng = ftanh(fmaf(rg, acc2[q] + bhn, xn));
                float h  = (1.0f - zg) * ng + zg * hprev[q];
                hprev[q] = h; hn[q] = h;
                if (t == lenr[q] - 1)
                    mrv16[(seq0 + rbase + q) * Hn + jh] = f2bf(h);
            }
            unsigned u01 = cvtpk_bf16(hn[0], hn[1]);
            unsigned u23 = cvtpk_bf16(hn[2], hn[3]);
            *(unsigned short*)(wb + woff[0]) = (unsigned short)u01;
            *(unsigned short*)(wb + woff[1]) = (unsigned short)(u01 >> 16);
            *(unsigned short*)(wb + woff[2]) = (unsigned short)u23;
            *(unsigned short*)(wb + woff[3]) = (unsigned short)(u23 >> 16);
            BAR();
        };

        for (int t = 0; t < Ln; t += 2) {
            step(t,     0, Ar, Az, An_, Al, Br, Bz, Bn_, Bl);
            step(t + 1, 1, Br, Bz, Bn_, Bl, Ar, Az, An_, Al);
        }
    } else {
        // ===== INTRA GRU: 1 wave = 1 sequence, fdot2, no barriers =====
        const int seq = blockIdx.x * 4 + w;   // 0..15
        const int j = lane;
        // Wh_x columns {j, 64+j, 128+j} packed f16 pairs along k (96 VGPRs)
        half2_t wf[3][32];
#pragma unroll
        for (int g = 0; g < 3; ++g)
#pragma unroll
            for (int p = 0; p < 32; ++p) {
                half2_t v;
                v[0] = (_Float16)Wh_x[(2 * p)     * G3 + g * 64 + j];
                v[1] = (_Float16)Wh_x[(2 * p + 1) * G3 + g * 64 + j];
                wf[g][p] = v;
            }
        const float bhr = bh_x[j], bhz = bh_x[64 + j], bhn = bh_x[128 + j];
        _Float16* hx = &hx_s[w][0];
        hx[j] = (_Float16)0.0f;
        float hmy = 0.0f;
        const float* qp = xw + seq * Sn * G3 + j;
        float* po = h_x + seq * Sn * Hn + j;
        float Ar, Az, An_, Br, Bz, Bn_;
        gload3(qp, Ar, Az, An_);   // t=0
        asm volatile("s_waitcnt lgkmcnt(0)" ::: "memory");  // hx zero visible

        auto istep = [&](int t, float& gr, float& gz, float& gn,
                         float& pr, float& pz, float& pn) {
            qp += G3;                       // t+1 (last iter: harmless overrun)
            gload3(qp, pr, pz, pn);
            // broadcast-read h vector (same-wave LDS; compiler inserts lgkm)
            uint4v qv[8];
#pragma unroll
            for (int i2 = 0; i2 < 8; ++i2) qv[i2] = ((const uint4v*)hx)[i2];
            float dr[4] = {0.f, 0.f, 0.f, 0.f};
            float dz[4] = {0.f, 0.f, 0.f, 0.f};
            float dn[4] = {0.f, 0.f, 0.f, 0.f};
#pragma unroll
            for (int i2 = 0; i2 < 8; ++i2) {
#pragma unroll
                for (int k = 0; k < 4; ++k) {
                    const int p = i2 * 4 + k;
                    half2_t hv = __builtin_bit_cast(half2_t, qv[i2][k]);
                    dr[p & 3] = __builtin_amdgcn_fdot2(hv, wf[0][p], dr[p & 3], false);
                    dz[p & 3] = __builtin_amdgcn_fdot2(hv, wf[1][p], dz[p & 3], false);
                    dn[p & 3] = __builtin_amdgcn_fdot2(hv, wf[2][p], dn[p & 3], false);
                }
            }
            float ghr = (dr[0] + dr[1]) + (dr[2] + dr[3]) + bhr;
            float ghz = (dz[0] + dz[1]) + (dz[2] + dz[3]) + bhz;
            float ghn = (dn[0] + dn[1]) + (dn[2] + dn[3]) + bhn;
            // previous step's loads (gr/gz/gn) have landed: <=4 outstanding
            // = 3 new loads + 1 store
            asm volatile("s_waitcnt vmcnt(4)" ::: "memory");
            __builtin_amdgcn_sched_barrier(0);
            float rg = fsig(gr + ghr);
            float zg = fsig(gz + ghz);
            float ng = ftanh(fmaf(rg, ghn, gn));
            float h  = (1.0f - zg) * ng + zg * hmy;
            hmy = h;
            po[t * Hn] = h;                 // global store (floats in vmcnt)
            hx[j] = (_Float16)h;            // same-wave ds_write
        };

        for (int t = 0; t < Sn; t += 2) {
            istep(t,     Ar, Az, An_, Br, Bz, Bn_);
            istep(t + 1, Br, Bz, Bn_, Ar, Az, An_);
        }
    }
}

// ---------------------------------------------------------------------------
// Kernel C: attention + MLP; 4 rows per block (weight-load amortization).
// ---------------------------------------------------------------------------
__global__ __launch_bounds__(256) void attn_mlp(
    const float* __restrict__ h_x, const unsigned short* __restrict__ mrv16,
    const float* __restrict__ emb, const int* __restrict__ inter_r,
    const float* __restrict__ y,
    const float* __restrict__ Wq,
    const float* __restrict__ Wo, const float* __restrict__ bo,
    const float* __restrict__ W1, const float* __restrict__ b1,
    const float* __restrict__ W2, const float* __restrict__ b2,
    const float* __restrict__ W3, const float* __restrict__ b3,
    float* __restrict__ out)
{
    const int r0 = blockIdx.x * 4;        // rows r0..r0+3
    const int tid = threadIdx.x;
    __shared__ float sh[4][64], ql[4][64], Ml[4][4][64], scl[4][4], al[4][4];
    __shared__ float vv[4][132], ol[4][64], z1[4][PH1n], z2[4][64];
    __shared__ int   rid[4][4];
    __shared__ float rlab[4][4];

    { int rr = tid >> 6, j = tid & 63; sh[rr][j] = h_x[(r0 + rr) * Hn + j]; }
    for (int i = tid; i < 4 * 4 * 64; i += 256) {
        int rr = i >> 8, r = (i >> 6) & 3, j = i & 63;
        Ml[rr][r][j] = bf2f(mrv16[((r0 + rr) * Rn + r) * Hn + j]);
    }
    if (tid < 16) {
        int rr = tid >> 2, r = tid & 3;
        rid[rr][r]  = inter_r[((r0 + rr) * Rn + r) * 2];
        rlab[rr][r] = (float)inter_r[((r0 + rr) * Rn + r) * 2 + 1];
    }
    __syncthreads();
    if (tid < 64) {
        const int j = tid;
        float a0 = 0.f, a1 = 0.f, a2 = 0.f, a3 = 0.f;
#pragma unroll 4
        for (int k = 0; k < 64; ++k) {
            float wv = Wq[k * Hn + j];
            a0 = fmaf(sh[0][k], wv, a0); a1 = fmaf(sh[1][k], wv, a1);
            a2 = fmaf(sh[2][k], wv, a2); a3 = fmaf(sh[3][k], wv, a3);
        }
        ql[0][j] = a0; ql[1][j] = a1; ql[2][j] = a2; ql[3][j] = a3;
    }
    __syncthreads();
    if (tid < 16) {
        int rr = tid >> 2, r = tid & 3;
        float a = 0.f;
#pragma unroll 8
        for (int k = 0; k < 64; ++k) a = fmaf(ql[rr][k], Ml[rr][r][k], a);
        scl[rr][r] = a * 0.125f;
    }
    __syncthreads();
    if (tid < 4) {
        const int rr = tid;
        float m = fmaxf(fmaxf(scl[rr][0], scl[rr][1]), fmaxf(scl[rr][2], scl[rr][3]));
        float s = 0.f, e[4];
#pragma unroll
        for (int r = 0; r < 4; ++r) { e[r] = __builtin_amdgcn_exp2f((scl[rr][r] - m) * 1.442695041f); s += e[r]; }
        float inv = __builtin_amdgcn_rcpf(s);
#pragma unroll
        for (int r = 0; r < 4; ++r) al[rr][r] = e[r] * inv;
    }
    __syncthreads();
    if (tid < 129) {
#pragma unroll
        for (int rr = 0; rr < 4; ++rr) {
            float a = 0.f;
#pragma unroll
            for (int r = 0; r < 4; ++r) {
                float val;
                if (tid < 64)       val = Ml[rr][r][tid];
                else if (tid < 128) val = emb[rid[rr][r] * En + (tid - 64)];
                else                val = rlab[rr][r];
                a = fmaf(al[rr][r], val, a);
            }
            vv[rr][tid] = a;
        }
    }
    __syncthreads();
    if (tid < 64) {
        const int j = tid;
        float a0 = bo[j], a1 = a0, a2 = a0, a3 = a0;
#pragma unroll 4
        for (int k = 0; k < 64; ++k) {
            float wv = Wo[k * Hn + j];
            a0 = fmaf(sh[0][k], wv, a0); a1 = fmaf(sh[1][k], wv, a1);
            a2 = fmaf(sh[2][k], wv, a2); a3 = fmaf(sh[3][k], wv, a3);
        }
#pragma unroll 4
        for (int k = 0; k < 129; ++k) {
            float wv = Wo[(64 + k) * Hn + j];
            a0 = fmaf(vv[0][k], wv, a0); a1 = fmaf(vv[1][k], wv, a1);
            a2 = fmaf(vv[2][k], wv, a2); a3 = fmaf(vv[3][k], wv, a3);
        }
        ol[0][j] = ftanh(a0); ol[1][j] = ftanh(a1);
        ol[2][j] = ftanh(a2); ol[3][j] = ftanh(a3);
    }
    __syncthreads();
    {
        const int j = tid;
        float a0 = b1[j], a1 = a0, a2 = a0, a3 = a0;
#pragma unroll 4
        for (int k = 0; k < 64; ++k) {
            float wv = W1[k * PH1n + j];
            a0 = fmaf(ol[0][k], wv, a0); a1 = fmaf(ol[1][k], wv, a1);
            a2 = fmaf(ol[2][k], wv, a2); a3 = fmaf(ol[3][k], wv, a3);
        }
        z1[0][j] = fmaxf(a0, 0.f); z1[1][j] = fmaxf(a1, 0.f);
        z1[2][j] = fmaxf(a2, 0.f); z1[3][j] = fmaxf(a3, 0.f);
    }
    __syncthreads();
    if (tid < 64) {
        const int j = tid;
        float a0 = b2[j], a1 = a0, a2 = a0, a3 = a0;
#pragma unroll 4
        for (int k = 0; k < PH1n; ++k) {
            float wv = W2[k * PH2n + j];
            a0 = fmaf(z1[0][k], wv, a0); a1 = fmaf(z1[1][k], wv, a1);
            a2 = fmaf(z1[2][k], wv, a2); a3 = fmaf(z1[3][k], wv, a3);
        }
        z2[0][j] = fmaxf(a0, 0.f); z2[1][j] = fmaxf(a1, 0.f);
        z2[2][j] = fmaxf(a2, 0.f); z2[3][j] = fmaxf(a3, 0.f);
    }
    __syncthreads();
    if (tid < 4) {
        const int rr = tid;
        float a = b3[0];
#pragma unroll 8
        for (int k = 0; k < 64; ++k) a = fmaf(z2[rr][k], W3[k], a);
        out[r0 + rr] = fsig(a);
        out[NROW + r0 + rr] = y[r0 + rr];
    }
}

// ---------------------------------------------------------------------------
extern "C" void kernel_launch(void* const* d_in, const int* in_sizes, int n_in,
                              void* d_out, int out_size, void* d_ws, size_t ws_size,
                              hipStream_t stream) {
    const int*   intra_x   = (const int*)d_in[0];
    const int*   inter_his = (const int*)d_in[1];
    const int*   inter_r   = (const int*)d_in[2];
    const float* y         = (const float*)d_in[3];
    const int*   inter_len = (const int*)d_in[5];
    const float* emb  = (const float*)d_in[6];
    const float* Wi_h = (const float*)d_in[7];
    const float* Wh_h = (const float*)d_in[8];
    const float* bi_h = (const float*)d_in[9];
    const float* bh_h = (const float*)d_in[10];
    const float* Wi_x = (const float*)d_in[11];
    const float* Wh_x = (const float*)d_in[12];
    const float* bi_x = (const float*)d_in[13];
    const float* bh_x = (const float*)d_in[14];
    const float* Wq = (const float*)d_in[15];
    const float* Wo = (const float*)d_in[16];
    const float* bo = (const float*)d_in[17];
    const float* W1 = (const float*)d_in[18];
    const float* b1 = (const float*)d_in[19];
    const float* W2 = (const float*)d_in[20];
    const float* b2 = (const float*)d_in[21];
    const float* W3 = (const float*)d_in[22];
    const float* b3 = (const float*)d_in[23];

    float* out = (float*)d_out;
    float* ws  = (float*)d_ws;
    // workspace (floats): pre_h 192000 | xw 393216 | mrv16 (524288 ushort =
    // 262144 float-slots) | h_x 131072  => 3.91 MB total
    float*          pre_h = ws;
    float*          xw    = ws + 192000;
    unsigned short* mrv16 = (unsigned short*)(ws + 585216);
    float*          h_x   = ws + 847360;

    precompute_tab<<<Vn + NROW, 192, 0, stream>>>(emb, Wi_h, bi_h, Wi_x, bi_x,
                                                  intra_x, y, pre_h, xw);
    gru_fused<<<4 + NSEQ / GP, 256, 0, stream>>>(pre_h, xw, inter_his, inter_len,
                                                 Wh_h, bh_h, Wi_h,
                                                 Wh_x, bh_x,
                                                 mrv16, h_x);
    attn_mlp<<<NROW / 4, 256, 0, stream>>>(h_x, mrv16, emb, inter_r, y,
                                           Wq, Wo, bo, W1, b1, W2, b2, W3, b3, out);
}